// Round 7
// baseline (344.805 us; speedup 1.0000x reference)
//
#include <hip/hip_runtime.h>

#define CH    288
#define CPG   9
#define IMH   64
#define IMW   64
#define HW    4096
#define NB    8
#define NPX   (NB * HW)
#define TILEB 18432u         // per 32-px micro-tile: 9 k-slabs x 2048 B
#define WSLAB 18432u         // weight slab per k0: 288 rows x 64 B
#define BN_EPS 1e-5f

typedef short bf16x8 __attribute__((ext_vector_type(8)));
typedef float f32x4  __attribute__((ext_vector_type(4)));

// ws layout (bytes)
#define XP_OFF   0u            // x_p / tmp_p bf16 packed tiles (18,874,368)
#define WIP_OFF  18874368u     // Wi_p  [9][288][64B] plain packed (165,888)
#define WOP_OFF  19040256u     // Wo_p  [9][288][64B] plain packed, scale-folded
#define S1_OFF   19206144u     // per-channel sum   f32 [288]
#define S2_OFF   19207296u     // per-channel sumsq f32 [288]
#define SC_OFF   19208448u     // scale f32 [288]
#define SH_OFF   19209600u     // shift f32 [288]
#define BO2_OFF  19210752u     // folded bias f32 [288]

__device__ __forceinline__ unsigned short f2b(float f) {
    unsigned int u = __float_as_uint(f);
    return (unsigned short)((u + 0x7fffu + ((u >> 16) & 1u)) >> 16);
}
__device__ __forceinline__ float b2f(unsigned short h) {
    return __uint_as_float(((unsigned int)h) << 16);
}
__device__ __forceinline__ f32x4 mfma16(bf16x8 a, bf16x8 b, f32x4 c) {
    return __builtin_amdgcn_mfma_f32_16x16x32_bf16(a, b, c, 0, 0, 0);
}

// ---------------------------------------------------------------------------
// K0: x f32 [b][c][p] -> xp bf16 micro-tiles [b*128+t][k0][px 32][64B plain]
// chunk qq of row px holds channels k0*32 + qq*8 .. +8.
// ---------------------------------------------------------------------------
__global__ __launch_bounds__(256) void k_transpose(const float* __restrict__ x,
                                                   char* __restrict__ xp) {
    __shared__ unsigned short T[32 * 296];   // [px][c], 592 B rows
    const int tid = threadIdx.x;
    const int p0  = blockIdx.x * 32;
    const int b   = blockIdx.y;
    #pragma unroll 1
    for (int it = 0; it < 9; ++it) {
        const int c   = it * 32 + (tid >> 3);
        const int px4 = (tid & 7) * 4;
        const float4 v = *(const float4*)(x + (size_t)(b * CH + c) * HW + p0 + px4);
        T[(px4 + 0) * 296 + c] = f2b(v.x);
        T[(px4 + 1) * 296 + c] = f2b(v.y);
        T[(px4 + 2) * 296 + c] = f2b(v.z);
        T[(px4 + 3) * 296 + c] = f2b(v.w);
    }
    __syncthreads();
    char* tile = xp + (size_t)(b * 128 + blockIdx.x) * TILEB;
    for (int idx = tid; idx < 1152; idx += 256) {
        const int k0 = idx >> 7;
        const int px = (idx >> 2) & 31;
        const int qq = idx & 3;
        *(uint4*)(tile + idx * 16) =
            *(const uint4*)((const char*)T + px * 592 + k0 * 64 + qq * 16);
    }
}

// ---------------------------------------------------------------------------
// K0b: Wi f32 -> Wi_p bf16 [k0][c][64B] plain
// ---------------------------------------------------------------------------
__global__ __launch_bounds__(256) void k_wi_pack(const float* __restrict__ Wi,
                                                 char* __restrict__ Wip) {
    const int idx = blockIdx.x * 256 + threadIdx.x;
    if (idx >= 10368) return;                  // 9*288*4 chunks
    const int k0  = idx / 1152;
    const int rem = idx - k0 * 1152;
    const int c   = rem >> 2;
    const int qq  = rem & 3;
    const float* src = Wi + (size_t)c * CH + k0 * 32 + qq * 8;
    const float4 a = *(const float4*)src;
    const float4 d = *(const float4*)(src + 4);
    unsigned short h[8] = {f2b(a.x), f2b(a.y), f2b(a.z), f2b(a.w),
                           f2b(d.x), f2b(d.y), f2b(d.z), f2b(d.w)};
    *(uint4*)(Wip + (size_t)idx * 16) = *(const uint4*)h;
}

// ---------------------------------------------------------------------------
// K1: MFMA GEMM1, NO LDS. Direct coalesced global frag loads (packed layout
// makes each wave frag load a contiguous 1KB block; weights L1/L2-resident).
// Block = 64 px x 288 ch (2 micro-tiles), 4 waves; wave = 32 px x 144 ch
// (M2 x N9 16x16 tiles, acc = 72 regs). BN stats: shfl + global atomics (r2
// pattern, measured clean).
// ---------------------------------------------------------------------------
__global__ __launch_bounds__(256) void k_gemm1(const char* __restrict__ Wip,
                                               const float* __restrict__ bi,
                                               char* __restrict__ xp,
                                               float* __restrict__ s1g,
                                               float* __restrict__ s2g) {
    const int tid  = threadIdx.x;
    const int wave = tid >> 6;
    const int lane = tid & 63;
    const int q    = lane >> 4;
    const int r    = lane & 15;
    const int pxh  = wave & 1;      // which 32-px micro-tile
    const int chh  = wave >> 1;     // 144-ch half

    char* tw = xp + (size_t)blockIdx.x * 2 * TILEB + pxh * TILEB;
    const char* wbase = Wip + (size_t)(chh * 144 + r) * 64 + q * 16;

    f32x4 acc[2][9];
    #pragma unroll
    for (int t = 0; t < 2; ++t)
        #pragma unroll
        for (int j = 0; j < 9; ++j) acc[t][j] = (f32x4)0.0f;

    for (int k0 = 0; k0 < 9; ++k0) {
        bf16x8 xf[2];
        #pragma unroll
        for (int t = 0; t < 2; ++t)
            xf[t] = *(const bf16x8*)(tw + k0 * 2048 + (t * 16 + r) * 64 + q * 16);
        #pragma unroll
        for (int j = 0; j < 9; ++j) {
            const bf16x8 wf = *(const bf16x8*)(wbase + (size_t)k0 * WSLAB + j * 1024);
            acc[0][j] = mfma16(wf, xf[0], acc[0][j]);
            acc[1][j] = mfma16(wf, xf[1], acc[1][j]);
        }
    }

    __syncthreads();   // all waves done reading the tiles before in-place store

    #pragma unroll 1
    for (int j = 0; j < 9; ++j) {
        const int cbase = chh * 144 + j * 16 + q * 4;
        const float4 b4 = *(const float4*)(bi + cbase);
        const int k0s = cbase >> 5;
        const int cof = (cbase & 31) * 2;
        float a1[4] = {0.f, 0.f, 0.f, 0.f}, a2[4] = {0.f, 0.f, 0.f, 0.f};
        #pragma unroll
        for (int t = 0; t < 2; ++t) {
            float v0 = fmaxf(acc[t][j][0] + b4.x, 0.0f);
            float v1 = fmaxf(acc[t][j][1] + b4.y, 0.0f);
            float v2 = fmaxf(acc[t][j][2] + b4.z, 0.0f);
            float v3 = fmaxf(acc[t][j][3] + b4.w, 0.0f);
            unsigned short h[4] = {f2b(v0), f2b(v1), f2b(v2), f2b(v3)};
            *(uint2*)(tw + k0s * 2048 + (t * 16 + r) * 64 + cof) = *(const uint2*)h;
            a1[0] += v0; a1[1] += v1; a1[2] += v2; a1[3] += v3;
            a2[0] += v0 * v0; a2[1] += v1 * v1; a2[2] += v2 * v2; a2[3] += v3 * v3;
        }
        #pragma unroll
        for (int m = 1; m < 16; m <<= 1) {
            #pragma unroll
            for (int i = 0; i < 4; ++i) {
                a1[i] += __shfl_xor(a1[i], m, 64);
                a2[i] += __shfl_xor(a2[i], m, 64);
            }
        }
        if (r == 0) {
            #pragma unroll
            for (int i = 0; i < 4; ++i) {
                atomicAdd(&s1g[cbase + i], a1[i]);
                atomicAdd(&s2g[cbase + i], a2[i]);
            }
        }
    }
}

// ---------------------------------------------------------------------------
// K2a: BN scale/shift
// ---------------------------------------------------------------------------
__global__ __launch_bounds__(320) void k_scale(const float* __restrict__ s1,
                                               const float* __restrict__ s2,
                                               const float* __restrict__ gamma,
                                               const float* __restrict__ beta,
                                               float* __restrict__ scale,
                                               float* __restrict__ shift) {
    const int c = threadIdx.x;
    if (c < CH) {
        const float inv  = 1.0f / (float)(NB * HW);
        const float mean = s1[c] * inv;
        const float var  = s2[c] * inv - mean * mean;
        const float rs   = rsqrtf(var + BN_EPS);
        const float sc   = gamma[c] * rs;
        scale[c] = sc;
        shift[c] = beta[c] - mean * sc;
    }
}

// ---------------------------------------------------------------------------
// K2b: Wo_p[k0][m][64B] = bf16(Wo[m][k]*scale[k]) plain; bo2 = bo + Wo@shift
// ---------------------------------------------------------------------------
__global__ __launch_bounds__(64) void k_fold(const float* __restrict__ Wo,
                                             const float* __restrict__ bo,
                                             const float* __restrict__ scale,
                                             const float* __restrict__ shift,
                                             char* __restrict__ Wop,
                                             float* __restrict__ bo2) {
    const int m = blockIdx.x;
    const int t = threadIdx.x;
    float s = 0.0f;
    for (int k = t; k < CH; k += 64) s += Wo[(size_t)m * CH + k] * shift[k];
    #pragma unroll
    for (int off = 32; off > 0; off >>= 1) s += __shfl_down(s, off, 64);
    if (t == 0) bo2[m] = bo[m] + s;
    if (t < 36) {
        const int k0 = t >> 2;
        const int qq = t & 3;
        const int kb = k0 * 32 + qq * 8;
        const float* src = Wo + (size_t)m * CH + kb;
        unsigned short h[8];
        #pragma unroll
        for (int i = 0; i < 8; ++i) h[i] = f2b(src[i] * scale[kb + i]);
        *(uint4*)(Wop + (size_t)k0 * WSLAB + m * 64 + qq * 16) = *(const uint4*)h;
    }
}

// ---------------------------------------------------------------------------
// K3: MFMA GEMM2 (no-LDS K-loop, same as K1) -> kerL in LDS -> involution.
// Block = 128 px (2 image rows, 4 micro-tiles) x 288 ch, 512 threads, 8 waves;
// wave = 32 px x 144 ch (M2 x N9, acc 72). kerL [288][132] shorts = 76032 B.
// ---------------------------------------------------------------------------
#define KLS 132
__global__ __launch_bounds__(512) void k_gemm2_invol(const char* __restrict__ xp,
                                                     const char* __restrict__ Wop,
                                                     const float* __restrict__ bo2,
                                                     const float* __restrict__ x,
                                                     float* __restrict__ out) {
    __shared__ unsigned short kerL[CH * KLS];   // 76032 B

    const int tid  = threadIdx.x;
    const int wave = tid >> 6;
    const int lane = tid & 63;
    const int q    = lane >> 4;
    const int r    = lane & 15;
    const int pq   = wave & 3;      // 32-px quarter
    const int chh  = wave >> 2;     // 144-ch half
    const int b    = blockIdx.x >> 5;
    const int h0   = (blockIdx.x & 31) * 2;

    const char* tw = xp + ((size_t)blockIdx.x * 4 + pq) * TILEB;
    const char* wbase = Wop + (size_t)(chh * 144 + r) * 64 + q * 16;

    f32x4 acc[2][9];
    #pragma unroll
    for (int t = 0; t < 2; ++t)
        #pragma unroll
        for (int j = 0; j < 9; ++j) acc[t][j] = (f32x4)0.0f;

    for (int k0 = 0; k0 < 9; ++k0) {
        bf16x8 xf[2];
        #pragma unroll
        for (int t = 0; t < 2; ++t)
            xf[t] = *(const bf16x8*)(tw + k0 * 2048 + (t * 16 + r) * 64 + q * 16);
        #pragma unroll
        for (int j = 0; j < 9; ++j) {
            const bf16x8 wf = *(const bf16x8*)(wbase + (size_t)k0 * WSLAB + j * 1024);
            acc[0][j] = mfma16(wf, xf[0], acc[0][j]);
            acc[1][j] = mfma16(wf, xf[1], acc[1][j]);
        }
    }

    // stage ker (+bias) into LDS: kerL[c][px 0..127]
    #pragma unroll
    for (int j = 0; j < 9; ++j) {
        const int cbase = chh * 144 + j * 16 + q * 4;
        const float4 bz = *(const float4*)(bo2 + cbase);
        #pragma unroll
        for (int t = 0; t < 2; ++t) {
            const int px = pq * 32 + t * 16 + r;
            kerL[(cbase + 0) * KLS + px] = f2b(acc[t][j][0] + bz.x);
            kerL[(cbase + 1) * KLS + px] = f2b(acc[t][j][1] + bz.y);
            kerL[(cbase + 2) * KLS + px] = f2b(acc[t][j][2] + bz.z);
            kerL[(cbase + 3) * KLS + px] = f2b(acc[t][j][3] + bz.w);
        }
    }
    __syncthreads();

    // involution: thread (g = tid>>4, tn = tid&15) handles 8 px (2 quads)
    const int g  = tid >> 4;    // group 0..31
    const int tn = tid & 15;
    #pragma unroll 1
    for (int quad = 0; quad < 2; ++quad) {
        const int px0 = tn * 8 + quad * 4;     // 0..124
        const int h   = h0 + (px0 >> 6);
        const int wb  = px0 & 63;
        uint2 kk[9];
        #pragma unroll
        for (int k = 0; k < 9; ++k)
            kk[k] = *(const uint2*)(kerL + (g * CPG + k) * KLS + px0);
        #pragma unroll 1
        for (int cc = 0; cc < 9; ++cc) {
            const int ch = g * CPG + cc;
            float xv[3][6];
            #pragma unroll
            for (int dr = 0; dr < 3; ++dr) {
                const int hh = h + dr - 1;
                const bool rv = (hh >= 0) && (hh < IMH);
                const float* xr = x + ((size_t)(b * CH + ch) * IMH + (rv ? hh : 0)) * IMW;
                if (rv) {
                    const float4 m4 = *(const float4*)(xr + wb);
                    xv[dr][1] = m4.x; xv[dr][2] = m4.y; xv[dr][3] = m4.z; xv[dr][4] = m4.w;
                    xv[dr][0] = (wb > 0)       ? xr[wb - 1] : 0.0f;
                    xv[dr][5] = (wb + 4 < IMW) ? xr[wb + 4] : 0.0f;
                } else {
                    #pragma unroll
                    for (int j2 = 0; j2 < 6; ++j2) xv[dr][j2] = 0.0f;
                }
            }
            float o[4] = {0.0f, 0.0f, 0.0f, 0.0f};
            #pragma unroll
            for (int k = 0; k < 9; ++k) {
                const int dr = k / 3, dc = k % 3;
                const unsigned short* ks = (const unsigned short*)&kk[k];
                #pragma unroll
                for (int j2 = 0; j2 < 4; ++j2)
                    o[j2] += b2f(ks[j2]) * xv[dr][j2 + dc];
            }
            float4 ov = {o[0], o[1], o[2], o[3]};
            *(float4*)(out + ((size_t)(b * CH + ch) * IMH + h) * IMW + wb) = ov;
        }
    }
}

// ---------------------------------------------------------------------------
extern "C" void kernel_launch(void* const* d_in, const int* in_sizes, int n_in,
                              void* d_out, int out_size, void* d_ws, size_t ws_size,
                              hipStream_t stream) {
    const float* x     = (const float*)d_in[0];
    const float* Wi    = (const float*)d_in[1];
    const float* bi    = (const float*)d_in[2];
    const float* gamma = (const float*)d_in[3];
    const float* beta  = (const float*)d_in[4];
    const float* Wo    = (const float*)d_in[5];
    const float* bo    = (const float*)d_in[6];
    float* out = (float*)d_out;

    char* ws = (char*)d_ws;
    char*  xp    = ws + XP_OFF;
    char*  Wip   = ws + WIP_OFF;
    char*  Wop   = ws + WOP_OFF;
    float* s1    = (float*)(ws + S1_OFF);
    float* s2    = (float*)(ws + S2_OFF);
    float* scale = (float*)(ws + SC_OFF);
    float* shift = (float*)(ws + SH_OFF);
    float* bo2   = (float*)(ws + BO2_OFF);

    k_transpose<<<dim3(128, NB), 256, 0, stream>>>(x, xp);
    k_wi_pack<<<dim3(41), 256, 0, stream>>>(Wi, Wip);
    hipMemsetAsync(ws + S1_OFF, 0, 2 * CH * sizeof(float), stream);
    k_gemm1<<<dim3(NPX / 64), 256, 0, stream>>>(Wip, bi, xp, s1, s2);
    k_scale<<<dim3(1), 320, 0, stream>>>(s1, s2, gamma, beta, scale, shift);
    k_fold<<<dim3(CH), 64, 0, stream>>>(Wo, bo, scale, shift, Wop, bo2);
    k_gemm2_invol<<<dim3(NB * 32), 512, 0, stream>>>(xp, Wop, bo2, x, out);
}